// Round 1
// 278.755 us; speedup vs baseline: 1.0142x; 1.0142x over previous
//
#include <hip/hip_runtime.h>
#include <hip/hip_bf16.h>
#include <cstdint>
#include <cstddef>

// Problem constants
#define S_LEN 2048
#define DMODEL 2048
#define NHEADS 8
#define DHEAD 128
#define INNER_DIM 1024
#define BATCH 2

typedef __bf16 bf16;
typedef __bf16 bf16x8 __attribute__((ext_vector_type(8)));
typedef __bf16 bf16x4 __attribute__((ext_vector_type(4)));
typedef float f32x4 __attribute__((ext_vector_type(4)));

#define VMCNT(n) asm volatile("s_waitcnt vmcnt(" #n ")" ::: "memory")
#define BAR()                                \
  do {                                       \
    asm volatile("" ::: "memory");           \
    __builtin_amdgcn_s_barrier();            \
    asm volatile("" ::: "memory");           \
  } while (0)

__device__ __forceinline__ void gload_lds16(const void* g, void* l) {
  __builtin_amdgcn_global_load_lds(
      (const __attribute__((address_space(1))) void*)g,
      (__attribute__((address_space(3))) void*)l, 16, 0, 0);
}

__device__ __forceinline__ float sigmoidf_(float x) {
  return 1.0f / (1.0f + expf(-x));
}

// ---------------------------------------------------------------------------
// Convert fp32 weights -> bf16 (Wq, Wk, Wv laid out contiguously, then Wo).
// ---------------------------------------------------------------------------
__global__ __launch_bounds__(256) void convert_w_kernel(
    const float* __restrict__ wq, const float* __restrict__ wk,
    const float* __restrict__ wv, const float* __restrict__ wo,
    bf16* __restrict__ wqkvb, bf16* __restrict__ wob) {
  size_t i4 = ((size_t)blockIdx.x * 256 + threadIdx.x) * 4;
  const float* src;
  bf16* dst;
  size_t off;
  if (i4 < 2097152UL)       { src = wq; dst = wqkvb;           off = i4; }
  else if (i4 < 4194304UL)  { src = wk; dst = wqkvb + 2097152; off = i4 - 2097152UL; }
  else if (i4 < 6291456UL)  { src = wv; dst = wqkvb + 4194304; off = i4 - 4194304UL; }
  else                      { src = wo; dst = wob;             off = i4 - 6291456UL; }
  float4 v = *(const float4*)(src + off);
  bf16x4 o;
  o[0] = (bf16)v.x; o[1] = (bf16)v.y; o[2] = (bf16)v.z; o[3] = (bf16)v.w;
  *(bf16x4*)(dst + off) = o;
}

// ---------------------------------------------------------------------------
// Per-head alpha.
// ---------------------------------------------------------------------------
__global__ __launch_bounds__(64) void alpha_kernel(
    const float* __restrict__ alpha_log, float* __restrict__ la_mean,
    float* __restrict__ la_d) {
  int h = blockIdx.x;
  int lane = threadIdx.x;
  float a1 = sigmoidf_(alpha_log[h * 128 + lane]);
  float a2 = sigmoidf_(alpha_log[h * 128 + 64 + lane]);
  la_d[h * 128 + lane] = logf(a1);
  la_d[h * 128 + 64 + lane] = logf(a2);
  float s = a1 + a2;
  for (int off = 32; off; off >>= 1) s += __shfl_down(s, off);
  if (lane == 0) la_mean[h] = logf(fmaxf(s * (1.0f / 128.0f), 1e-6f));
}

// ---------------------------------------------------------------------------
// beta[n,h] = sigmoid(x[n,:].Wb[h,:] + bb[h]); also emits xb = bf16(x).
// ---------------------------------------------------------------------------
__global__ __launch_bounds__(64) void beta_xb_kernel(
    const float* __restrict__ x, const float* __restrict__ Wb,
    const float* __restrict__ bbias, float* __restrict__ beta,
    bf16* __restrict__ xb) {
  int n = blockIdx.x;
  int lane = threadIdx.x;
  float acc[8];
#pragma unroll
  for (int h = 0; h < 8; h++) acc[h] = 0.0f;
  const float4* x4 = (const float4*)(x + (size_t)n * DMODEL);
  bf16* xbr = xb + (size_t)n * DMODEL;
  for (int d4 = lane; d4 < DMODEL / 4; d4 += 64) {
    float4 xv = x4[d4];
    bf16x4 o;
    o[0] = (bf16)xv.x; o[1] = (bf16)xv.y; o[2] = (bf16)xv.z; o[3] = (bf16)xv.w;
    *(bf16x4*)(xbr + d4 * 4) = o;
#pragma unroll
    for (int h = 0; h < 8; h++) {
      float4 wv = ((const float4*)(Wb + (size_t)h * DMODEL))[d4];
      acc[h] += xv.x * wv.x + xv.y * wv.y + xv.z * wv.z + xv.w * wv.w;
    }
  }
#pragma unroll
  for (int off = 32; off; off >>= 1)
#pragma unroll
    for (int h = 0; h < 8; h++) acc[h] += __shfl_down(acc[h], off);
  if (lane == 0) {
#pragma unroll
    for (int h = 0; h < 8; h++)
      beta[(size_t)n * 8 + h] = sigmoidf_(acc[h] + bbias[h]);
  }
}

// ---------------------------------------------------------------------------
// QKV projection: 256x256-tile 8-phase bf16 GEMM (T2+T3+T4+T5 template).
// C = A(4096x2048) . B(3072x2048)^T, written as 3 z-slices (q,k,v) of
// [4096][1024] bf16; z==2 additionally writes the transposed vt copy.
//
// Geometry: BM=BN=256, BK=64, 8 waves (2M x 4N), per-wave 128x64 output
// (acc[8][4] f32x4). LDS 128 KiB: 2 buffers x (A 32KB + B 32KB).
// Per K-tile, 4 phases; phase p (qm=p>>1, qn=p&1):
//   12 ds_read_b128 (wave quadrant: 4 m-frags x 2ks + 2 n-frags x 2ks)
//   2 global_load_lds stage issues for tile t+1:
//     p0: A-quarter q0, p1: B-quarter q0, p2: B-quarter q1, p3: A-quarter q1
//   barrier; setprio(1); 16 MFMA; setprio(0); [vmcnt] ; barrier
// Counted vmcnt: vmcnt(4) at p1, vmcnt(2) at p3 (drain only prologue + last
// tile). Schedule proof: region R first read at tile t+1 phase P is staged
// >=2 counted checks before P (Aq0@t-p0, Bq0@t-p1 covered by C(t)=vmcnt(2);
// Bq1@t-p2 covered by C(t); Aq1@t-p3 covered by vmcnt(4) at t+1-p1).
// LDS read swizzle: 16B-granule XOR (row&7) — conflict-free (8 lanes per
// granule = ds_read_b128 floor); staging pre-swizzles the GLOBAL source so
// the LDS destination stays linear (rule #21).
// ---------------------------------------------------------------------------
#define QKV_K 2048
#define QKV_NT 32  // K / 64
#define QKV_TN 12  // 3072 / 256
#define QKV_TM 16  // 4096 / 256

__global__ __launch_bounds__(512, 2) void qkv_gemm8p_kernel(
    const bf16* __restrict__ A, const bf16* __restrict__ Bm,
    bf16* __restrict__ C, bf16* __restrict__ vt) {
  __shared__ __align__(16) bf16 smem[2][32768];  // 2 x 64KB

  // XCD-aware bijective remap: 192 blocks = 8 XCDs x 24
  const int id = blockIdx.x;
  const int wg = (id & 7) * 24 + (id >> 3);
  const int tile_m = (wg / QKV_TN) * 256;
  const int tile_n = (wg % QKV_TN) * 256;

  const int tid = threadIdx.x;
  const int lane = tid & 63;
  const int w = tid >> 6;
  const int wm = w >> 2;  // 0..1
  const int wn = w & 3;   // 0..3
  const int lr = lane & 15;
  const int kq = lane >> 4;

  const bf16* Ag = A + (size_t)tile_m * QKV_K;
  const bf16* Bg = Bm + (size_t)tile_n * QKV_K;

  // staging lane constants: each gload issue = 8 rows x 128B; lane l covers
  // row_local l>>3, LDS slot l&7; global granule pre-swizzled (l&7)^(l>>3).
  const int srow = lane >> 3;
  const int sgo = ((lane & 7) ^ srow) * 8;  // bf16 offset of global granule

  f32x4 acc[8][4];
#pragma unroll
  for (int i = 0; i < 8; i++)
#pragma unroll
    for (int j = 0; j < 4; j++) acc[i][j] = (f32x4){0.f, 0.f, 0.f, 0.f};

  auto stageA = [&](int buf, int k0, int qms) {
#pragma unroll
    for (int u = 0; u < 2; ++u) {
      const int b8 = wm * 16 + qms * 8 + wn * 2 + u;
      const bf16* gp = Ag + (size_t)(b8 * 8 + srow) * QKV_K + k0 + sgo;
      gload_lds16(gp, &smem[buf][b8 * 512]);
    }
  };
  auto stageB = [&](int buf, int k0, int qns) {
#pragma unroll
    for (int u = 0; u < 2; ++u) {
      const int b8 = wn * 8 + qns * 4 + wm * 2 + u;
      const bf16* gp = Bg + (size_t)(b8 * 8 + srow) * QKV_K + k0 + sgo;
      gload_lds16(gp, &smem[buf][16384 + b8 * 512]);
    }
  };

  // prologue: stage all of tile 0, drain once
  stageA(0, 0, 0);
  stageB(0, 0, 0);
  stageB(0, 0, 1);
  stageA(0, 0, 1);
  VMCNT(0);
  BAR();

  for (int t = 0; t < QKV_NT; ++t) {
    const int buf = t & 1;
    const int k0n = (t + 1) * 64;
    const bool hn = (t + 1 < QKV_NT);
    const bf16* ldsA = smem[buf];
    const bf16* ldsB = smem[buf] + 16384;
#pragma unroll
    for (int p = 0; p < 4; ++p) {
      const int qm = p >> 1;
      const int qn = p & 1;
      bf16x8 af[4][2], bfq[2][2];
#pragma unroll
      for (int mi = 0; mi < 4; ++mi)
#pragma unroll
        for (int ks = 0; ks < 2; ++ks)
          af[mi][ks] = *(const bf16x8*)&ldsA[(wm * 128 + qm * 64 + mi * 16 + lr) * 64 +
                                             (((ks * 4 + kq) ^ (lr & 7)) * 8)];
#pragma unroll
      for (int ni = 0; ni < 2; ++ni)
#pragma unroll
        for (int ks = 0; ks < 2; ++ks)
          bfq[ni][ks] = *(const bf16x8*)&ldsB[(wn * 64 + qn * 32 + ni * 16 + lr) * 64 +
                                              (((ks * 4 + kq) ^ (lr & 7)) * 8)];
      if (hn) {
        if (p == 0) stageA(buf ^ 1, k0n, 0);
        else if (p == 1) stageB(buf ^ 1, k0n, 0);
        else if (p == 2) stageB(buf ^ 1, k0n, 1);
        else stageA(buf ^ 1, k0n, 1);
      }
      BAR();
      __builtin_amdgcn_s_setprio(1);
#pragma unroll
      for (int mi = 0; mi < 4; ++mi)
#pragma unroll
        for (int ni = 0; ni < 2; ++ni)
#pragma unroll
          for (int ks = 0; ks < 2; ++ks)
            acc[qm * 4 + mi][qn * 2 + ni] = __builtin_amdgcn_mfma_f32_16x16x32_bf16(
                af[mi][ks], bfq[ni][ks], acc[qm * 4 + mi][qn * 2 + ni], 0, 0, 0);
      __builtin_amdgcn_s_setprio(0);
      if (p == 1) {
        if (t == QKV_NT - 1) VMCNT(0);
        else VMCNT(4);
      }
      if (p == 3) VMCNT(2);
      BAR();
    }
  }

  // epilogue: acc -> q/kk/vv (+ vt for z==2)
  const int rb = (lane >> 4) * 4;
#pragma unroll
  for (int mig = 0; mig < 8; ++mig) {
    const int row0 = tile_m + wm * 128 + (mig >> 2) * 64 + (mig & 3) * 16 + rb;
#pragma unroll
    for (int nig = 0; nig < 4; ++nig) {
      const int col = tile_n + wn * 64 + (nig >> 1) * 32 + (nig & 1) * 16 + lr;
      const int z = col >> 10;
      const int cz = col & 1023;
      bf16* Cz = C + (size_t)z * 4194304UL;
#pragma unroll
      for (int r2 = 0; r2 < 4; ++r2)
        Cz[(size_t)(row0 + r2) * 1024 + cz] = (bf16)acc[mig][nig][r2];
      if (z == 2) {
        const int bb2 = row0 >> 11;
        const int ss = row0 & 2047;
        bf16x4 o4;
#pragma unroll
        for (int r2 = 0; r2 < 4; ++r2) o4[r2] = (bf16)acc[mig][nig][r2];
        *(bf16x4*)&vt[(((size_t)bb2 * 8 + (cz >> 7)) * 128 + (cz & 127)) * 2048 +
                      ss] = o4;
      }
    }
  }
}

// ---------------------------------------------------------------------------
// bf16 NT GEMM (round-3 config: BK=32, XOR bank swizzle, XCD tile swizzle).
// Retained for the output projection (obf=0, fp32 C).
// ---------------------------------------------------------------------------
__global__ __launch_bounds__(256) void gemm_bt_kernel(
    const bf16* __restrict__ A, const bf16* __restrict__ Bm, void* Cv, int K,
    int N, size_t strideB, size_t strideC, int obf, bf16* __restrict__ vt) {
  // ---- XCD-aware tile remap (bijective) ----
  const int id = blockIdx.x + gridDim.x * (blockIdx.y + gridDim.y * blockIdx.z);
  const int xcd = id & 7;
  const int s = id >> 3;
  const int xs = gridDim.x >> 2;
  const int ys = gridDim.y >> 1;
  const int perz = xs * ys;
  const int z = s / perz;
  const int r = s - z * perz;
  const int tx = (xcd & 3) * xs + (r % xs);
  const int ty = (xcd >> 2) * ys + (r / xs);
  const int tile_n = tx * 128;
  const int tile_m = ty * 128;

  const bf16* Bp = Bm + (size_t)z * strideB;
  const int tid = threadIdx.x;
  const int lane = tid & 63;
  const int wv = tid >> 6;

  __shared__ bf16 As[128 * 32];
  __shared__ bf16 Bs[128 * 32];

  f32x4 acc[4][4];
#pragma unroll
  for (int i = 0; i < 4; i++)
#pragma unroll
    for (int j = 0; j < 4; j++) acc[i][j] = (f32x4){0.f, 0.f, 0.f, 0.f};

  const int wm = (wv >> 1) * 64;
  const int wn = (wv & 1) * 64;
  const int lr = lane & 15;
  const int kq = lane >> 4;
  const int swzA = ((wm + lr) >> 1) & 3;
  const int swzB = ((wn + lr) >> 1) & 3;
  const int kA = (kq ^ swzA) * 8;
  const int kB = (kq ^ swzB) * 8;

  const int ar = wv * 32 + (lane >> 2);
  const int g = ((lane & 3) ^ ((ar >> 1) & 3)) * 8;
  const bf16* Ag = A + (size_t)(tile_m + ar) * K + g;
  const bf16* Bg = Bp + (size_t)(tile_n + ar) * K + g;
  bf16* AsW = &As[wv * 1024];
  bf16* BsW = &Bs[wv * 1024];

  for (int k0 = 0; k0 < K; k0 += 32) {
    gload_lds16(Ag + k0, AsW);
    gload_lds16(Ag + (size_t)16 * K + k0, AsW + 512);
    gload_lds16(Bg + k0, BsW);
    gload_lds16(Bg + (size_t)16 * K + k0, BsW + 512);
    __syncthreads();
    bf16x8 af[4], bfr[4];
#pragma unroll
    for (int mi = 0; mi < 4; mi++)
      af[mi] = *(const bf16x8*)&As[(wm + mi * 16 + lr) * 32 + kA];
#pragma unroll
    for (int ni = 0; ni < 4; ni++)
      bfr[ni] = *(const bf16x8*)&Bs[(wn + ni * 16 + lr) * 32 + kB];
#pragma unroll
    for (int mi = 0; mi < 4; mi++)
#pragma unroll
      for (int ni = 0; ni < 4; ni++)
        acc[mi][ni] = __builtin_amdgcn_mfma_f32_16x16x32_bf16(
            af[mi], bfr[ni], acc[mi][ni], 0, 0, 0);
    __syncthreads();
  }

  const int crow0 = tile_m + wm + (lane >> 4) * 4;
  const int ccol = tile_n + wn + (lane & 15);
  if (obf) {
    bf16* Cb = (bf16*)Cv + (size_t)z * strideC;
#pragma unroll
    for (int mi = 0; mi < 4; mi++)
#pragma unroll
      for (int ni = 0; ni < 4; ni++)
#pragma unroll
        for (int r2 = 0; r2 < 4; r2++)
          Cb[(size_t)(crow0 + mi * 16 + r2) * N + ccol + ni * 16] =
              (bf16)acc[mi][ni][r2];
    if (z == 2) {
#pragma unroll
      for (int mi = 0; mi < 4; mi++) {
        int row0 = crow0 + mi * 16;
        int bb2 = row0 >> 11, ss = row0 & 2047;
#pragma unroll
        for (int ni = 0; ni < 4; ni++) {
          int col = ccol + ni * 16;
          bf16x4 o4;
#pragma unroll
          for (int r2 = 0; r2 < 4; r2++) o4[r2] = (bf16)acc[mi][ni][r2];
          *(bf16x4*)&vt[(((size_t)bb2 * 8 + (col >> 7)) * 128 + (col & 127)) *
                            2048 +
                        ss] = o4;
        }
      }
    }
  } else {
    float* Cf = (float*)Cv + (size_t)z * strideC;
#pragma unroll
    for (int mi = 0; mi < 4; mi++)
#pragma unroll
      for (int ni = 0; ni < 4; ni++)
#pragma unroll
        for (int r2 = 0; r2 < 4; r2++)
          Cf[(size_t)(crow0 + mi * 16 + r2) * N + ccol + ni * 16] =
              acc[mi][ni][r2];
  }
}

// ---------------------------------------------------------------------------
// RoPE in place on bf16 q and k.
// ---------------------------------------------------------------------------
__global__ __launch_bounds__(256) void rope_kernel(bf16* __restrict__ q,
                                                   bf16* __restrict__ k) {
  int idx = blockIdx.x * 256 + threadIdx.x;  // < 524288
  int j0 = (idx & 15) * 4;
  int nh = idx >> 4;  // n*8 + h, n < 4096
  int s = (nh >> 3) & (S_LEN - 1);
  size_t base = (size_t)nh * 128 + j0;
  bf16x4 qa = *(bf16x4*)&q[base], qb = *(bf16x4*)&q[base + 64];
  bf16x4 ka = *(bf16x4*)&k[base], kb = *(bf16x4*)&k[base + 64];
#pragma unroll
  for (int jj = 0; jj < 4; jj++) {
    float inv = expf(-(float)(j0 + jj) * (9.210340371976184f / 64.0f));
    float f = (float)s * inv;
    float sn, c;
    sincosf(f, &sn, &c);
    float q1 = (float)qa[jj], q2 = (float)qb[jj];
    qa[jj] = (bf16)(q1 * c - q2 * sn);
    qb[jj] = (bf16)(q2 * c + q1 * sn);
    float k1 = (float)ka[jj], k2 = (float)kb[jj];
    ka[jj] = (bf16)(k1 * c - k2 * sn);
    kb[jj] = (bf16)(k2 * c + k1 * sn);
  }
  *(bf16x4*)&q[base] = qa;
  *(bf16x4*)&q[base + 64] = qb;
  *(bf16x4*)&k[base] = ka;
  *(bf16x4*)&k[base + 64] = kb;
}

// ---------------------------------------------------------------------------
// MFMA banded-decay attention. One block per (s-block 64, h, b); 4 waves,
// each wave owns 16 q rows. QK^T and PV via 16x16x32 bf16 MFMA.
// ---------------------------------------------------------------------------
__global__ __launch_bounds__(256) void attn_mfma_kernel(
    const bf16* __restrict__ q, const bf16* __restrict__ k,
    const bf16* __restrict__ vt, const float* __restrict__ beta,
    const float* __restrict__ la_mean, bf16* __restrict__ outb) {
  const int s0 = blockIdx.x * 64;
  const int h = blockIdx.y;
  const int b = blockIdx.z;
  const int tid = threadIdx.x;
  const int w = tid >> 6;
  const int lane = tid & 63;
  const int lr = lane & 15;
  const int kq = lane >> 4;  // quad
  const float la = la_mean[h];

  __shared__ __align__(16) bf16 Ps[4][2][16][72];

  const int sg = s0 + w * 16;
  const size_t qbase =
      ((size_t)b * S_LEN + (sg + lr)) * INNER_DIM + h * 128 + kq * 8;
  bf16x8 aq[4];
#pragma unroll
  for (int ks = 0; ks < 4; ks++)
    aq[ks] = *(const bf16x8*)&q[qbase + ks * 32];

  f32x4 O[8];
#pragma unroll
  for (int en = 0; en < 8; en++) O[en] = (f32x4){0.f, 0.f, 0.f, 0.f};

  const size_t kbase = (size_t)b * S_LEN * INNER_DIM + h * 128 + kq * 8;
  const size_t vtbase = ((size_t)b * 8 + h) * 128 * 2048;

#pragma unroll
  for (int tile = 0; tile < 2; tile++) {
    const int tb = s0 - 64 + tile * 64;
    f32x4 sc[4];
#pragma unroll
    for (int nt = 0; nt < 4; nt++) sc[nt] = (f32x4){0.f, 0.f, 0.f, 0.f};
#pragma unroll
    for (int nt = 0; nt < 4; nt++) {
      int t = tb + nt * 16 + lr;
      int tc = t > 0 ? t : 0;
#pragma unroll
      for (int ks = 0; ks < 4; ks++) {
        bf16x8 bk = *(const bf16x8*)&k[kbase + (size_t)tc * INNER_DIM + ks * 32];
        sc[nt] = __builtin_amdgcn_mfma_f32_16x16x32_bf16(aq[ks], bk, sc[nt],
                                                         0, 0, 0);
      }
    }
#pragma unroll
    for (int nt = 0; nt < 4; nt++) {
      int t = tb + nt * 16 + lr;
      int tc = t > 0 ? t : 0;
      float bt = beta[((size_t)b * S_LEN + tc) * 8 + h];
#pragma unroll
      for (int reg = 0; reg < 4; reg++) {
        int qrow = sg + kq * 4 + reg;
        int td = qrow - t;
        float wgt = 0.0f;
        if (t >= 0 && td >= 0 && td < 64)
          wgt = sc[nt][reg] * __expf((float)td * la) * bt;
        Ps[w][tile][kq * 4 + reg][nt * 16 + lr] = (bf16)wgt;
      }
    }
    __syncthreads();
    bf16x8 ap[2];
#pragma unroll
    for (int ks2 = 0; ks2 < 2; ks2++)
      ap[ks2] = *(const bf16x8*)&Ps[w][tile][lr][ks2 * 32 + kq * 8];
#pragma unroll
    for (int en = 0; en < 8; en++) {
#pragma unroll
      for (int ks2 = 0; ks2 < 2; ks2++) {
        int t0f = tb + ks2 * 32 + kq * 8;
        int tcf = t0f > 0 ? t0f : 0;
        bf16x8 bv = *(const bf16x8*)&vt[vtbase + (size_t)(en * 16 + lr) * 2048 +
                                        tcf];
        O[en] = __builtin_amdgcn_mfma_f32_16x16x32_bf16(ap[ks2], bv, O[en], 0,
                                                        0, 0);
      }
    }
  }
  const size_t obase = (size_t)b * S_LEN * INNER_DIM + h * 128;
#pragma unroll
  for (int en = 0; en < 8; en++) {
#pragma unroll
    for (int reg = 0; reg < 4; reg++) {
      int qrow = sg + kq * 4 + reg;
      outb[obase + (size_t)qrow * INNER_DIM + en * 16 + lr] =
          (bf16)O[en][reg];
    }
  }
}

// ---------------------------------------------------------------------------
// Stage 1: partial state per 32-step chunk (bf16 k/v inputs), no atomics.
// ---------------------------------------------------------------------------
__global__ __launch_bounds__(256) void state_partial_kernel(
    const bf16* __restrict__ k, const bf16* __restrict__ v,
    const float* __restrict__ beta, const float* __restrict__ la_d,
    float* __restrict__ part) {
  const int bh = blockIdx.x;
  const int chunk = blockIdx.y;
  const int b = bh >> 3, h = bh & 7;
  const int t0 = S_LEN - 512 + chunk * 32;
  const int tid = threadIdx.x;
  const int d = tid >> 1;
  const int eh = (tid & 1) * 64;

  __shared__ float ks[32][128];
  __shared__ float vsm[32][128];
  __shared__ float bs[32];

  const size_t bh_off = ((size_t)b * S_LEN) * INNER_DIM + (size_t)h * 128;
  for (int u = tid; u < 32 * 16; u += 256) {
    int r = u >> 4, c8 = (u & 15) * 8;
    bf16x8 kv = *(const bf16x8*)&k[bh_off + (size_t)(t0 + r) * INNER_DIM + c8];
    bf16x8 vv = *(const bf16x8*)&v[bh_off + (size_t)(t0 + r) * INNER_DIM + c8];
#pragma unroll
    for (int j = 0; j < 8; j++) {
      ks[r][c8 + j] = (float)kv[j];
      vsm[r][c8 + j] = (float)vv[j];
    }
  }
  if (tid < 32) bs[tid] = beta[((size_t)b * S_LEN + t0 + tid) * 8 + h];
  __syncthreads();

  const float lad = la_d[h * 128 + d];
  float acc[64];
#pragma unroll
  for (int e = 0; e < 64; e++) acc[e] = 0.0f;

  for (int tl = 0; tl < 32; tl++) {
    int m = (S_LEN - 1) - (t0 + tl);
    float f = __expf((float)m * lad);
    float coef = bs[tl] * ks[tl][d] * f;
    if (coef != 0.0f) {
#pragma unroll
      for (int e = 0; e < 64; e += 4) {
        float4 vv = *(const float4*)&vsm[tl][eh + e];
        acc[e + 0] = fmaf(coef, vv.x, acc[e + 0]);
        acc[e + 1] = fmaf(coef, vv.y, acc[e + 1]);
        acc[e + 2] = fmaf(coef, vv.z, acc[e + 2]);
        acc[e + 3] = fmaf(coef, vv.w, acc[e + 3]);
      }
    }
  }
  float* pp = part + (((size_t)chunk * 16 + bh) * 16384 + (size_t)d * 128 + eh);
#pragma unroll
  for (int e = 0; e < 64; e += 4) {
    float4 o = {acc[e + 0], acc[e + 1], acc[e + 2], acc[e + 3]};
    *(float4*)&pp[e] = o;
  }
}

// ---------------------------------------------------------------------------
// Stage 2: sum the 16 chunk partials into the final state.
// ---------------------------------------------------------------------------
__global__ __launch_bounds__(256) void state_reduce_kernel(
    const float* __restrict__ part, float* __restrict__ state) {
  size_t off = ((size_t)blockIdx.x * 256 + threadIdx.x) * 4;
  float4 s = {0.f, 0.f, 0.f, 0.f};
#pragma unroll
  for (int c = 0; c < 16; c++) {
    float4 p = *(const float4*)&part[(size_t)c * 262144 + off];
    s.x += p.x; s.y += p.y; s.z += p.z; s.w += p.w;
  }
  *(float4*)&state[off] = s;
}

// ---------------------------------------------------------------------------
extern "C" void kernel_launch(void* const* d_in, const int* in_sizes, int n_in,
                              void* d_out, int out_size, void* d_ws,
                              size_t ws_size, hipStream_t stream) {
  const float* x = (const float*)d_in[0];
  const float* Wq = (const float*)d_in[1];
  const float* Wk = (const float*)d_in[2];
  const float* Wv = (const float*)d_in[3];
  const float* Wo = (const float*)d_in[4];
  const float* Wb = (const float*)d_in[5];
  const float* bb = (const float*)d_in[6];
  const float* alog = (const float*)d_in[7];
  float* out = (float*)d_out;

  char* ws = (char*)d_ws;
  bf16* xb = (bf16*)(ws);                      // 16 MB
  float* part = (float*)(ws);                  // reuses xb after QKV GEMM
  bf16* wqkvb = (bf16*)(ws + 16777216UL);      // 12 MB
  bf16* wob = (bf16*)(ws + 29360128UL);        // 4 MB
  bf16* q = (bf16*)(ws + 33554432UL);          // 8 MB
  bf16* kk = (bf16*)(ws + 41943040UL);         // 8 MB
  bf16* vv = (bf16*)(ws + 50331648UL);         // 8 MB
  bf16* attnb = (bf16*)(ws + 58720256UL);      // 8 MB
  bf16* vt = (bf16*)(ws + 67108864UL);         // 8 MB (V transposed)
  float* beta = (float*)(ws + 75497472UL);     // 128 KB
  float* la_mean = (float*)(ws + 75628544UL);  // 32 B
  float* la_d = (float*)(ws + 75628800UL);     // 4 KB

  convert_w_kernel<<<8192, 256, 0, stream>>>(Wq, Wk, Wv, Wo, wqkvb, wob);
  alpha_kernel<<<8, 64, 0, stream>>>(alog, la_mean, la_d);
  beta_xb_kernel<<<BATCH * S_LEN, 64, 0, stream>>>(x, Wb, bb, beta, xb);
  // fused QKV GEMM (256^2 8-phase) -> bf16 q/kk/vv (+ vt transposed copy)
  qkv_gemm8p_kernel<<<QKV_TM * QKV_TN, 512, 0, stream>>>(xb, wqkvb, q, vt);
  rope_kernel<<<2048, 256, 0, stream>>>(q, kk);
  attn_mfma_kernel<<<dim3(S_LEN / 64, NHEADS, BATCH), 256, 0, stream>>>(
      q, kk, vt, beta, la_mean, attnb);
  state_partial_kernel<<<dim3(16, 16), 256, 0, stream>>>(kk, vv, beta, la_d,
                                                         part);
  state_reduce_kernel<<<256, 256, 0, stream>>>(part, out + 8388608);
  gemm_bt_kernel<<<dim3(DMODEL / 128, (BATCH * S_LEN) / 128, 1), 256, 0,
                   stream>>>(attnb, wob, out, INNER_DIM, DMODEL, 0, 0, 0,
                             nullptr);
}

// Round 2
// 269.052 us; speedup vs baseline: 1.0508x; 1.0361x over previous
//
#include <hip/hip_runtime.h>
#include <hip/hip_bf16.h>
#include <cstdint>
#include <cstddef>

// Problem constants
#define S_LEN 2048
#define DMODEL 2048
#define NHEADS 8
#define DHEAD 128
#define INNER_DIM 1024
#define BATCH 2

typedef __bf16 bf16;
typedef __bf16 bf16x8 __attribute__((ext_vector_type(8)));
typedef __bf16 bf16x4 __attribute__((ext_vector_type(4)));
typedef float f32x4 __attribute__((ext_vector_type(4)));

#define VMCNT(n) asm volatile("s_waitcnt vmcnt(" #n ")" ::: "memory")
#define BAR()                                \
  do {                                       \
    asm volatile("" ::: "memory");           \
    __builtin_amdgcn_s_barrier();            \
    asm volatile("" ::: "memory");           \
  } while (0)

__device__ __forceinline__ void gload_lds16(const void* g, void* l) {
  __builtin_amdgcn_global_load_lds(
      (const __attribute__((address_space(1))) void*)g,
      (__attribute__((address_space(3))) void*)l, 16, 0, 0);
}

__device__ __forceinline__ float sigmoidf_(float x) {
  return 1.0f / (1.0f + expf(-x));
}

// ---------------------------------------------------------------------------
// Convert fp32 weights -> bf16 (Wq, Wk, Wv laid out contiguously, then Wo).
// ---------------------------------------------------------------------------
__global__ __launch_bounds__(256) void convert_w_kernel(
    const float* __restrict__ wq, const float* __restrict__ wk,
    const float* __restrict__ wv, const float* __restrict__ wo,
    bf16* __restrict__ wqkvb, bf16* __restrict__ wob) {
  size_t i4 = ((size_t)blockIdx.x * 256 + threadIdx.x) * 4;
  const float* src;
  bf16* dst;
  size_t off;
  if (i4 < 2097152UL)       { src = wq; dst = wqkvb;           off = i4; }
  else if (i4 < 4194304UL)  { src = wk; dst = wqkvb + 2097152; off = i4 - 2097152UL; }
  else if (i4 < 6291456UL)  { src = wv; dst = wqkvb + 4194304; off = i4 - 4194304UL; }
  else                      { src = wo; dst = wob;             off = i4 - 6291456UL; }
  float4 v = *(const float4*)(src + off);
  bf16x4 o;
  o[0] = (bf16)v.x; o[1] = (bf16)v.y; o[2] = (bf16)v.z; o[3] = (bf16)v.w;
  *(bf16x4*)(dst + off) = o;
}

// ---------------------------------------------------------------------------
// Per-head alpha.
// ---------------------------------------------------------------------------
__global__ __launch_bounds__(64) void alpha_kernel(
    const float* __restrict__ alpha_log, float* __restrict__ la_mean,
    float* __restrict__ la_d) {
  int h = blockIdx.x;
  int lane = threadIdx.x;
  float a1 = sigmoidf_(alpha_log[h * 128 + lane]);
  float a2 = sigmoidf_(alpha_log[h * 128 + 64 + lane]);
  la_d[h * 128 + lane] = logf(a1);
  la_d[h * 128 + 64 + lane] = logf(a2);
  float s = a1 + a2;
  for (int off = 32; off; off >>= 1) s += __shfl_down(s, off);
  if (lane == 0) la_mean[h] = logf(fmaxf(s * (1.0f / 128.0f), 1e-6f));
}

// ---------------------------------------------------------------------------
// beta[n,h] = sigmoid(x[n,:].Wb[h,:] + bb[h]); also emits xb = bf16(x).
// ---------------------------------------------------------------------------
__global__ __launch_bounds__(64) void beta_xb_kernel(
    const float* __restrict__ x, const float* __restrict__ Wb,
    const float* __restrict__ bbias, float* __restrict__ beta,
    bf16* __restrict__ xb) {
  int n = blockIdx.x;
  int lane = threadIdx.x;
  float acc[8];
#pragma unroll
  for (int h = 0; h < 8; h++) acc[h] = 0.0f;
  const float4* x4 = (const float4*)(x + (size_t)n * DMODEL);
  bf16* xbr = xb + (size_t)n * DMODEL;
  for (int d4 = lane; d4 < DMODEL / 4; d4 += 64) {
    float4 xv = x4[d4];
    bf16x4 o;
    o[0] = (bf16)xv.x; o[1] = (bf16)xv.y; o[2] = (bf16)xv.z; o[3] = (bf16)xv.w;
    *(bf16x4*)(xbr + d4 * 4) = o;
#pragma unroll
    for (int h = 0; h < 8; h++) {
      float4 wv = ((const float4*)(Wb + (size_t)h * DMODEL))[d4];
      acc[h] += xv.x * wv.x + xv.y * wv.y + xv.z * wv.z + xv.w * wv.w;
    }
  }
#pragma unroll
  for (int off = 32; off; off >>= 1)
#pragma unroll
    for (int h = 0; h < 8; h++) acc[h] += __shfl_down(acc[h], off);
  if (lane == 0) {
#pragma unroll
    for (int h = 0; h < 8; h++)
      beta[(size_t)n * 8 + h] = sigmoidf_(acc[h] + bbias[h]);
  }
}

// ---------------------------------------------------------------------------
// QKV projection: 256x256-tile 8-phase bf16 GEMM (T2+T3+T4+T5 template).
// C = A(4096x2048) . B(3072x2048)^T, written as 3 z-slices (q,k,v) of
// [4096][1024] bf16; z==2 additionally writes the transposed vt copy.
//
// Round-2 restructure: phase walk (qm0,qn0)->(qm0,qn1)->(qm1,qn1)->(qm1,qn0)
// keeps fragments live across the two phases that reuse them:
//   p0: read A-q0 (8 b128) + B-q0 (4)   stage A-q0'   MFMA acc[0..3][0..1]
//   p1: read B-q1 (4)                   stage B-q0'   MFMA acc[0..3][2..3]
//   p2: read A-q1 (8, overwrites A-q0)  stage B-q1'   MFMA acc[4..7][2..3]
//   p3: (no reads; B-q0 still live)     stage A-q1'   MFMA acc[4..7][0..1]
// => 24 ds_read_b128 / wave / K-tile (was 48; minimum is 24).
// vmcnt ledger (2 loads per stage op, issue order A0,B0,B1,A1 per tile):
//   p0: vmcnt(4)  -> drains B1 staged 3 phases ago (read next phase at p1)
//   p1: vmcnt(4)  -> drains A1 (read at p2)
//   p2: (none)
//   p3: vmcnt(4)  -> drains next tile's A0+B0 (read at t+1 p0)
// Last tile: vmcnt(0) at p0 (no new stages shift the counts).
// LDS read swizzle: 16B-granule XOR (row&7) — conflict-free; staging
// pre-swizzles the GLOBAL source so LDS destination stays linear.
// ---------------------------------------------------------------------------
#define QKV_K 2048
#define QKV_NT 32  // K / 64
#define QKV_TN 12  // 3072 / 256
#define QKV_TM 16  // 4096 / 256

__global__ __launch_bounds__(512, 2) void qkv_gemm8p_kernel(
    const bf16* __restrict__ A, const bf16* __restrict__ Bm,
    bf16* __restrict__ C, bf16* __restrict__ vt) {
  __shared__ __align__(16) bf16 smem[2][32768];  // 2 x 64KB

  // XCD-aware bijective remap: 192 blocks = 8 XCDs x 24
  const int id = blockIdx.x;
  const int wg = (id & 7) * 24 + (id >> 3);
  const int tile_m = (wg / QKV_TN) * 256;
  const int tile_n = (wg % QKV_TN) * 256;

  const int tid = threadIdx.x;
  const int lane = tid & 63;
  const int w = tid >> 6;
  const int wm = w >> 2;  // 0..1
  const int wn = w & 3;   // 0..3
  const int lr = lane & 15;
  const int kq = lane >> 4;

  const bf16* Ag = A + (size_t)tile_m * QKV_K;
  const bf16* Bg = Bm + (size_t)tile_n * QKV_K;

  // staging lane constants: each gload issue = 8 rows x 128B; lane l covers
  // row_local l>>3, LDS slot l&7; global granule pre-swizzled (l&7)^(l>>3).
  const int srow = lane >> 3;
  const int sgo = ((lane & 7) ^ srow) * 8;  // bf16 offset of global granule

  f32x4 acc[8][4];
#pragma unroll
  for (int i = 0; i < 8; i++)
#pragma unroll
    for (int j = 0; j < 4; j++) acc[i][j] = (f32x4){0.f, 0.f, 0.f, 0.f};

  auto stageA = [&](int buf, int k0, int qms) {
#pragma unroll
    for (int u = 0; u < 2; ++u) {
      const int b8 = wm * 16 + qms * 8 + wn * 2 + u;
      const bf16* gp = Ag + (size_t)(b8 * 8 + srow) * QKV_K + k0 + sgo;
      gload_lds16(gp, &smem[buf][b8 * 512]);
    }
  };
  auto stageB = [&](int buf, int k0, int qns) {
#pragma unroll
    for (int u = 0; u < 2; ++u) {
      const int b8 = wn * 8 + qns * 4 + wm * 2 + u;
      const bf16* gp = Bg + (size_t)(b8 * 8 + srow) * QKV_K + k0 + sgo;
      gload_lds16(gp, &smem[buf][16384 + b8 * 512]);
    }
  };

  // prologue: stage all of tile 0, drain once
  stageA(0, 0, 0);
  stageB(0, 0, 0);
  stageB(0, 0, 1);
  stageA(0, 0, 1);
  VMCNT(0);
  BAR();

  for (int t = 0; t < QKV_NT; ++t) {
    const int buf = t & 1;
    const int k0n = (t + 1) * 64;
    const bool hn = (t + 1 < QKV_NT);
    const bf16* ldsA = smem[buf];
    const bf16* ldsB = smem[buf] + 16384;

    bf16x8 af[4][2], b0[2][2], b1[2][2];

    // -------- phase 0: read A-q0 + B-q0; stage A-q0(next); MFMA (0,0) -----
#pragma unroll
    for (int mi = 0; mi < 4; ++mi)
#pragma unroll
      for (int ks = 0; ks < 2; ++ks)
        af[mi][ks] = *(const bf16x8*)&ldsA[(wm * 128 + mi * 16 + lr) * 64 +
                                           (((ks * 4 + kq) ^ (lr & 7)) * 8)];
#pragma unroll
    for (int ni = 0; ni < 2; ++ni)
#pragma unroll
      for (int ks = 0; ks < 2; ++ks)
        b0[ni][ks] = *(const bf16x8*)&ldsB[(wn * 64 + ni * 16 + lr) * 64 +
                                           (((ks * 4 + kq) ^ (lr & 7)) * 8)];
    if (hn) stageA(buf ^ 1, k0n, 0);
    BAR();
    __builtin_amdgcn_s_setprio(1);
#pragma unroll
    for (int mi = 0; mi < 4; ++mi)
#pragma unroll
      for (int ni = 0; ni < 2; ++ni)
#pragma unroll
        for (int ks = 0; ks < 2; ++ks)
          acc[mi][ni] = __builtin_amdgcn_mfma_f32_16x16x32_bf16(
              af[mi][ks], b0[ni][ks], acc[mi][ni], 0, 0, 0);
    __builtin_amdgcn_s_setprio(0);
    if (hn) VMCNT(4);
    else VMCNT(0);
    BAR();

    // -------- phase 1: read B-q1; stage B-q0(next); MFMA (0,1) ------------
#pragma unroll
    for (int ni = 0; ni < 2; ++ni)
#pragma unroll
      for (int ks = 0; ks < 2; ++ks)
        b1[ni][ks] = *(const bf16x8*)&ldsB[(wn * 64 + 32 + ni * 16 + lr) * 64 +
                                           (((ks * 4 + kq) ^ (lr & 7)) * 8)];
    if (hn) stageB(buf ^ 1, k0n, 0);
    BAR();
    __builtin_amdgcn_s_setprio(1);
#pragma unroll
    for (int mi = 0; mi < 4; ++mi)
#pragma unroll
      for (int ni = 0; ni < 2; ++ni)
#pragma unroll
        for (int ks = 0; ks < 2; ++ks)
          acc[mi][2 + ni] = __builtin_amdgcn_mfma_f32_16x16x32_bf16(
              af[mi][ks], b1[ni][ks], acc[mi][2 + ni], 0, 0, 0);
    __builtin_amdgcn_s_setprio(0);
    VMCNT(4);
    BAR();

    // -------- phase 2: read A-q1; stage B-q1(next); MFMA (1,1) ------------
#pragma unroll
    for (int mi = 0; mi < 4; ++mi)
#pragma unroll
      for (int ks = 0; ks < 2; ++ks)
        af[mi][ks] = *(const bf16x8*)&ldsA[(wm * 128 + 64 + mi * 16 + lr) * 64 +
                                           (((ks * 4 + kq) ^ (lr & 7)) * 8)];
    if (hn) stageB(buf ^ 1, k0n, 1);
    BAR();
    __builtin_amdgcn_s_setprio(1);
#pragma unroll
    for (int mi = 0; mi < 4; ++mi)
#pragma unroll
      for (int ni = 0; ni < 2; ++ni)
#pragma unroll
        for (int ks = 0; ks < 2; ++ks)
          acc[4 + mi][2 + ni] = __builtin_amdgcn_mfma_f32_16x16x32_bf16(
              af[mi][ks], b1[ni][ks], acc[4 + mi][2 + ni], 0, 0, 0);
    __builtin_amdgcn_s_setprio(0);
    BAR();

    // -------- phase 3: no reads (B-q0 live); stage A-q1(next); MFMA (1,0) -
    if (hn) stageA(buf ^ 1, k0n, 1);
    BAR();
    __builtin_amdgcn_s_setprio(1);
#pragma unroll
    for (int mi = 0; mi < 4; ++mi)
#pragma unroll
      for (int ni = 0; ni < 2; ++ni)
#pragma unroll
        for (int ks = 0; ks < 2; ++ks)
          acc[4 + mi][ni] = __builtin_amdgcn_mfma_f32_16x16x32_bf16(
              af[mi][ks], b0[ni][ks], acc[4 + mi][ni], 0, 0, 0);
    __builtin_amdgcn_s_setprio(0);
    if (hn) VMCNT(4);
    BAR();
  }

  // epilogue: acc -> q/kk/vv (+ vt for z==2)
  const int rb = (lane >> 4) * 4;
#pragma unroll
  for (int mig = 0; mig < 8; ++mig) {
    const int row0 = tile_m + wm * 128 + (mig >> 2) * 64 + (mig & 3) * 16 + rb;
#pragma unroll
    for (int nig = 0; nig < 4; ++nig) {
      const int col = tile_n + wn * 64 + (nig >> 1) * 32 + (nig & 1) * 16 + lr;
      const int z = col >> 10;
      const int cz = col & 1023;
      bf16* Cz = C + (size_t)z * 4194304UL;
#pragma unroll
      for (int r2 = 0; r2 < 4; ++r2)
        Cz[(size_t)(row0 + r2) * 1024 + cz] = (bf16)acc[mig][nig][r2];
      if (z == 2) {
        const int bb2 = row0 >> 11;
        const int ss = row0 & 2047;
        bf16x4 o4;
#pragma unroll
        for (int r2 = 0; r2 < 4; ++r2) o4[r2] = (bf16)acc[mig][nig][r2];
        *(bf16x4*)&vt[(((size_t)bb2 * 8 + (cz >> 7)) * 128 + (cz & 127)) * 2048 +
                      ss] = o4;
      }
    }
  }
}

// ---------------------------------------------------------------------------
// bf16 NT GEMM (round-3 config: BK=32, XOR bank swizzle, XCD tile swizzle).
// Retained for the output projection (obf=0, fp32 C).
// ---------------------------------------------------------------------------
__global__ __launch_bounds__(256) void gemm_bt_kernel(
    const bf16* __restrict__ A, const bf16* __restrict__ Bm, void* Cv, int K,
    int N, size_t strideB, size_t strideC, int obf, bf16* __restrict__ vt) {
  // ---- XCD-aware tile remap (bijective) ----
  const int id = blockIdx.x + gridDim.x * (blockIdx.y + gridDim.y * blockIdx.z);
  const int xcd = id & 7;
  const int s = id >> 3;
  const int xs = gridDim.x >> 2;
  const int ys = gridDim.y >> 1;
  const int perz = xs * ys;
  const int z = s / perz;
  const int r = s - z * perz;
  const int tx = (xcd & 3) * xs + (r % xs);
  const int ty = (xcd >> 2) * ys + (r / xs);
  const int tile_n = tx * 128;
  const int tile_m = ty * 128;

  const bf16* Bp = Bm + (size_t)z * strideB;
  const int tid = threadIdx.x;
  const int lane = tid & 63;
  const int wv = tid >> 6;

  __shared__ bf16 As[128 * 32];
  __shared__ bf16 Bs[128 * 32];

  f32x4 acc[4][4];
#pragma unroll
  for (int i = 0; i < 4; i++)
#pragma unroll
    for (int j = 0; j < 4; j++) acc[i][j] = (f32x4){0.f, 0.f, 0.f, 0.f};

  const int wm = (wv >> 1) * 64;
  const int wn = (wv & 1) * 64;
  const int lr = lane & 15;
  const int kq = lane >> 4;
  const int swzA = ((wm + lr) >> 1) & 3;
  const int swzB = ((wn + lr) >> 1) & 3;
  const int kA = (kq ^ swzA) * 8;
  const int kB = (kq ^ swzB) * 8;

  const int ar = wv * 32 + (lane >> 2);
  const int g = ((lane & 3) ^ ((ar >> 1) & 3)) * 8;
  const bf16* Ag = A + (size_t)(tile_m + ar) * K + g;
  const bf16* Bg = Bp + (size_t)(tile_n + ar) * K + g;
  bf16* AsW = &As[wv * 1024];
  bf16* BsW = &Bs[wv * 1024];

  for (int k0 = 0; k0 < K; k0 += 32) {
    gload_lds16(Ag + k0, AsW);
    gload_lds16(Ag + (size_t)16 * K + k0, AsW + 512);
    gload_lds16(Bg + k0, BsW);
    gload_lds16(Bg + (size_t)16 * K + k0, BsW + 512);
    __syncthreads();
    bf16x8 af[4], bfr[4];
#pragma unroll
    for (int mi = 0; mi < 4; mi++)
      af[mi] = *(const bf16x8*)&As[(wm + mi * 16 + lr) * 32 + kA];
#pragma unroll
    for (int ni = 0; ni < 4; ni++)
      bfr[ni] = *(const bf16x8*)&Bs[(wn + ni * 16 + lr) * 32 + kB];
#pragma unroll
    for (int mi = 0; mi < 4; mi++)
#pragma unroll
      for (int ni = 0; ni < 4; ni++)
        acc[mi][ni] = __builtin_amdgcn_mfma_f32_16x16x32_bf16(
            af[mi], bfr[ni], acc[mi][ni], 0, 0, 0);
    __syncthreads();
  }

  const int crow0 = tile_m + wm + (lane >> 4) * 4;
  const int ccol = tile_n + wn + (lane & 15);
  if (obf) {
    bf16* Cb = (bf16*)Cv + (size_t)z * strideC;
#pragma unroll
    for (int mi = 0; mi < 4; mi++)
#pragma unroll
      for (int ni = 0; ni < 4; ni++)
#pragma unroll
        for (int r2 = 0; r2 < 4; r2++)
          Cb[(size_t)(crow0 + mi * 16 + r2) * N + ccol + ni * 16] =
              (bf16)acc[mi][ni][r2];
    if (z == 2) {
#pragma unroll
      for (int mi = 0; mi < 4; mi++) {
        int row0 = crow0 + mi * 16;
        int bb2 = row0 >> 11, ss = row0 & 2047;
#pragma unroll
        for (int ni = 0; ni < 4; ni++) {
          int col = ccol + ni * 16;
          bf16x4 o4;
#pragma unroll
          for (int r2 = 0; r2 < 4; r2++) o4[r2] = (bf16)acc[mi][ni][r2];
          *(bf16x4*)&vt[(((size_t)bb2 * 8 + (col >> 7)) * 128 + (col & 127)) *
                            2048 +
                        ss] = o4;
        }
      }
    }
  } else {
    float* Cf = (float*)Cv + (size_t)z * strideC;
#pragma unroll
    for (int mi = 0; mi < 4; mi++)
#pragma unroll
      for (int ni = 0; ni < 4; ni++)
#pragma unroll
        for (int r2 = 0; r2 < 4; r2++)
          Cf[(size_t)(crow0 + mi * 16 + r2) * N + ccol + ni * 16] =
              acc[mi][ni][r2];
  }
}

// ---------------------------------------------------------------------------
// RoPE in place on bf16 q and k.
// ---------------------------------------------------------------------------
__global__ __launch_bounds__(256) void rope_kernel(bf16* __restrict__ q,
                                                   bf16* __restrict__ k) {
  int idx = blockIdx.x * 256 + threadIdx.x;  // < 524288
  int j0 = (idx & 15) * 4;
  int nh = idx >> 4;  // n*8 + h, n < 4096
  int s = (nh >> 3) & (S_LEN - 1);
  size_t base = (size_t)nh * 128 + j0;
  bf16x4 qa = *(bf16x4*)&q[base], qb = *(bf16x4*)&q[base + 64];
  bf16x4 ka = *(bf16x4*)&k[base], kb = *(bf16x4*)&k[base + 64];
#pragma unroll
  for (int jj = 0; jj < 4; jj++) {
    float inv = expf(-(float)(j0 + jj) * (9.210340371976184f / 64.0f));
    float f = (float)s * inv;
    float sn, c;
    sincosf(f, &sn, &c);
    float q1 = (float)qa[jj], q2 = (float)qb[jj];
    qa[jj] = (bf16)(q1 * c - q2 * sn);
    qb[jj] = (bf16)(q2 * c + q1 * sn);
    float k1 = (float)ka[jj], k2 = (float)kb[jj];
    ka[jj] = (bf16)(k1 * c - k2 * sn);
    kb[jj] = (bf16)(k2 * c + k1 * sn);
  }
  *(bf16x4*)&q[base] = qa;
  *(bf16x4*)&q[base + 64] = qb;
  *(bf16x4*)&k[base] = ka;
  *(bf16x4*)&k[base + 64] = kb;
}

// ---------------------------------------------------------------------------
// MFMA banded-decay attention. One block per (s-block 64, h, b); 4 waves,
// each wave owns 16 q rows. QK^T and PV via 16x16x32 bf16 MFMA.
// ---------------------------------------------------------------------------
__global__ __launch_bounds__(256) void attn_mfma_kernel(
    const bf16* __restrict__ q, const bf16* __restrict__ k,
    const bf16* __restrict__ vt, const float* __restrict__ beta,
    const float* __restrict__ la_mean, bf16* __restrict__ outb) {
  const int s0 = blockIdx.x * 64;
  const int h = blockIdx.y;
  const int b = blockIdx.z;
  const int tid = threadIdx.x;
  const int w = tid >> 6;
  const int lane = tid & 63;
  const int lr = lane & 15;
  const int kq = lane >> 4;  // quad
  const float la = la_mean[h];

  __shared__ __align__(16) bf16 Ps[4][2][16][72];

  const int sg = s0 + w * 16;
  const size_t qbase =
      ((size_t)b * S_LEN + (sg + lr)) * INNER_DIM + h * 128 + kq * 8;
  bf16x8 aq[4];
#pragma unroll
  for (int ks = 0; ks < 4; ks++)
    aq[ks] = *(const bf16x8*)&q[qbase + ks * 32];

  f32x4 O[8];
#pragma unroll
  for (int en = 0; en < 8; en++) O[en] = (f32x4){0.f, 0.f, 0.f, 0.f};

  const size_t kbase = (size_t)b * S_LEN * INNER_DIM + h * 128 + kq * 8;
  const size_t vtbase = ((size_t)b * 8 + h) * 128 * 2048;

#pragma unroll
  for (int tile = 0; tile < 2; tile++) {
    const int tb = s0 - 64 + tile * 64;
    f32x4 sc[4];
#pragma unroll
    for (int nt = 0; nt < 4; nt++) sc[nt] = (f32x4){0.f, 0.f, 0.f, 0.f};
#pragma unroll
    for (int nt = 0; nt < 4; nt++) {
      int t = tb + nt * 16 + lr;
      int tc = t > 0 ? t : 0;
#pragma unroll
      for (int ks = 0; ks < 4; ks++) {
        bf16x8 bk = *(const bf16x8*)&k[kbase + (size_t)tc * INNER_DIM + ks * 32];
        sc[nt] = __builtin_amdgcn_mfma_f32_16x16x32_bf16(aq[ks], bk, sc[nt],
                                                         0, 0, 0);
      }
    }
#pragma unroll
    for (int nt = 0; nt < 4; nt++) {
      int t = tb + nt * 16 + lr;
      int tc = t > 0 ? t : 0;
      float bt = beta[((size_t)b * S_LEN + tc) * 8 + h];
#pragma unroll
      for (int reg = 0; reg < 4; reg++) {
        int qrow = sg + kq * 4 + reg;
        int td = qrow - t;
        float wgt = 0.0f;
        if (t >= 0 && td >= 0 && td < 64)
          wgt = sc[nt][reg] * __expf((float)td * la) * bt;
        Ps[w][tile][kq * 4 + reg][nt * 16 + lr] = (bf16)wgt;
      }
    }
    __syncthreads();
    bf16x8 ap[2];
#pragma unroll
    for (int ks2 = 0; ks2 < 2; ks2++)
      ap[ks2] = *(const bf16x8*)&Ps[w][tile][lr][ks2 * 32 + kq * 8];
#pragma unroll
    for (int en = 0; en < 8; en++) {
#pragma unroll
      for (int ks2 = 0; ks2 < 2; ks2++) {
        int t0f = tb + ks2 * 32 + kq * 8;
        int tcf = t0f > 0 ? t0f : 0;
        bf16x8 bv = *(const bf16x8*)&vt[vtbase + (size_t)(en * 16 + lr) * 2048 +
                                        tcf];
        O[en] = __builtin_amdgcn_mfma_f32_16x16x32_bf16(ap[ks2], bv, O[en], 0,
                                                        0, 0);
      }
    }
  }
  const size_t obase = (size_t)b * S_LEN * INNER_DIM + h * 128;
#pragma unroll
  for (int en = 0; en < 8; en++) {
#pragma unroll
    for (int reg = 0; reg < 4; reg++) {
      int qrow = sg + kq * 4 + reg;
      outb[obase + (size_t)qrow * INNER_DIM + en * 16 + lr] =
          (bf16)O[en][reg];
    }
  }
}

// ---------------------------------------------------------------------------
// Stage 1: partial state per 32-step chunk (bf16 k/v inputs), no atomics.
// ---------------------------------------------------------------------------
__global__ __launch_bounds__(256) void state_partial_kernel(
    const bf16* __restrict__ k, const bf16* __restrict__ v,
    const float* __restrict__ beta, const float* __restrict__ la_d,
    float* __restrict__ part) {
  const int bh = blockIdx.x;
  const int chunk = blockIdx.y;
  const int b = bh >> 3, h = bh & 7;
  const int t0 = S_LEN - 512 + chunk * 32;
  const int tid = threadIdx.x;
  const int d = tid >> 1;
  const int eh = (tid & 1) * 64;

  __shared__ float ks[32][128];
  __shared__ float vsm[32][128];
  __shared__ float bs[32];

  const size_t bh_off = ((size_t)b * S_LEN) * INNER_DIM + (size_t)h * 128;
  for (int u = tid; u < 32 * 16; u += 256) {
    int r = u >> 4, c8 = (u & 15) * 8;
    bf16x8 kv = *(const bf16x8*)&k[bh_off + (size_t)(t0 + r) * INNER_DIM + c8];
    bf16x8 vv = *(const bf16x8*)&v[bh_off + (size_t)(t0 + r) * INNER_DIM + c8];
#pragma unroll
    for (int j = 0; j < 8; j++) {
      ks[r][c8 + j] = (float)kv[j];
      vsm[r][c8 + j] = (float)vv[j];
    }
  }
  if (tid < 32) bs[tid] = beta[((size_t)b * S_LEN + t0 + tid) * 8 + h];
  __syncthreads();

  const float lad = la_d[h * 128 + d];
  float acc[64];
#pragma unroll
  for (int e = 0; e < 64; e++) acc[e] = 0.0f;

  for (int tl = 0; tl < 32; tl++) {
    int m = (S_LEN - 1) - (t0 + tl);
    float f = __expf((float)m * lad);
    float coef = bs[tl] * ks[tl][d] * f;
    if (coef != 0.0f) {
#pragma unroll
      for (int e = 0; e < 64; e += 4) {
        float4 vv = *(const float4*)&vsm[tl][eh + e];
        acc[e + 0] = fmaf(coef, vv.x, acc[e + 0]);
        acc[e + 1] = fmaf(coef, vv.y, acc[e + 1]);
        acc[e + 2] = fmaf(coef, vv.z, acc[e + 2]);
        acc[e + 3] = fmaf(coef, vv.w, acc[e + 3]);
      }
    }
  }
  float* pp = part + (((size_t)chunk * 16 + bh) * 16384 + (size_t)d * 128 + eh);
#pragma unroll
  for (int e = 0; e < 64; e += 4) {
    float4 o = {acc[e + 0], acc[e + 1], acc[e + 2], acc[e + 3]};
    *(float4*)&pp[e] = o;
  }
}

// ---------------------------------------------------------------------------
// Stage 2: sum the 16 chunk partials into the final state.
// ---------------------------------------------------------------------------
__global__ __launch_bounds__(256) void state_reduce_kernel(
    const float* __restrict__ part, float* __restrict__ state) {
  size_t off = ((size_t)blockIdx.x * 256 + threadIdx.x) * 4;
  float4 s = {0.f, 0.f, 0.f, 0.f};
#pragma unroll
  for (int c = 0; c < 16; c++) {
    float4 p = *(const float4*)&part[(size_t)c * 262144 + off];
    s.x += p.x; s.y += p.y; s.z += p.z; s.w += p.w;
  }
  *(float4*)&state[off] = s;
}

// ---------------------------------------------------------------------------
extern "C" void kernel_launch(void* const* d_in, const int* in_sizes, int n_in,
                              void* d_out, int out_size, void* d_ws,
                              size_t ws_size, hipStream_t stream) {
  const float* x = (const float*)d_in[0];
  const float* Wq = (const float*)d_in[1];
  const float* Wk = (const float*)d_in[2];
  const float* Wv = (const float*)d_in[3];
  const float* Wo = (const float*)d_in[4];
  const float* Wb = (const float*)d_in[5];
  const float* bb = (const float*)d_in[6];
  const float* alog = (const float*)d_in[7];
  float* out = (float*)d_out;

  char* ws = (char*)d_ws;
  bf16* xb = (bf16*)(ws);                      // 16 MB
  float* part = (float*)(ws);                  // reuses xb after QKV GEMM
  bf16* wqkvb = (bf16*)(ws + 16777216UL);      // 12 MB
  bf16* wob = (bf16*)(ws + 29360128UL);        // 4 MB
  bf16* q = (bf16*)(ws + 33554432UL);          // 8 MB
  bf16* kk = (bf16*)(ws + 41943040UL);         // 8 MB
  bf16* vv = (bf16*)(ws + 50331648UL);         // 8 MB
  bf16* attnb = (bf16*)(ws + 58720256UL);      // 8 MB
  bf16* vt = (bf16*)(ws + 67108864UL);         // 8 MB (V transposed)
  float* beta = (float*)(ws + 75497472UL);     // 128 KB
  float* la_mean = (float*)(ws + 75628544UL);  // 32 B
  float* la_d = (float*)(ws + 75628800UL);     // 4 KB

  convert_w_kernel<<<8192, 256, 0, stream>>>(Wq, Wk, Wv, Wo, wqkvb, wob);
  alpha_kernel<<<8, 64, 0, stream>>>(alog, la_mean, la_d);
  beta_xb_kernel<<<BATCH * S_LEN, 64, 0, stream>>>(x, Wb, bb, beta, xb);
  // fused QKV GEMM (256^2 8-phase) -> bf16 q/kk/vv (+ vt transposed copy)
  qkv_gemm8p_kernel<<<QKV_TM * QKV_TN, 512, 0, stream>>>(xb, wqkvb, q, vt);
  rope_kernel<<<2048, 256, 0, stream>>>(q, kk);
  attn_mfma_kernel<<<dim3(S_LEN / 64, NHEADS, BATCH), 256, 0, stream>>>(
      q, kk, vt, beta, la_mean, attnb);
  state_partial_kernel<<<dim3(16, 16), 256, 0, stream>>>(kk, vv, beta, la_d,
                                                         part);
  state_reduce_kernel<<<256, 256, 0, stream>>>(part, out + 8388608);
  gemm_bt_kernel<<<dim3(DMODEL / 128, (BATCH * S_LEN) / 128, 1), 256, 0,
                   stream>>>(attnb, wob, out, INNER_DIM, DMODEL, 0, 0, 0,
                             nullptr);
}

// Round 4
// 263.255 us; speedup vs baseline: 1.0740x; 1.0220x over previous
//
#include <hip/hip_runtime.h>
#include <hip/hip_bf16.h>
#include <cstdint>
#include <cstddef>

// Problem constants
#define S_LEN 2048
#define DMODEL 2048
#define NHEADS 8
#define DHEAD 128
#define INNER_DIM 1024
#define BATCH 2

typedef __bf16 bf16;
typedef __bf16 bf16x8 __attribute__((ext_vector_type(8)));
typedef __bf16 bf16x4 __attribute__((ext_vector_type(4)));
typedef float f32x4 __attribute__((ext_vector_type(4)));

#define VMCNT(n) asm volatile("s_waitcnt vmcnt(" #n ")" ::: "memory")
#define BAR()                                \
  do {                                       \
    asm volatile("" ::: "memory");           \
    __builtin_amdgcn_s_barrier();            \
    asm volatile("" ::: "memory");           \
  } while (0)

__device__ __forceinline__ void gload_lds16(const void* g, void* l) {
  __builtin_amdgcn_global_load_lds(
      (const __attribute__((address_space(1))) void*)g,
      (__attribute__((address_space(3))) void*)l, 16, 0, 0);
}

__device__ __forceinline__ float sigmoidf_(float x) {
  return 1.0f / (1.0f + expf(-x));
}

// ---------------------------------------------------------------------------
// Convert fp32 weights -> bf16 (Wq, Wk, Wv laid out contiguously, then Wo).
// ---------------------------------------------------------------------------
__global__ __launch_bounds__(256) void convert_w_kernel(
    const float* __restrict__ wq, const float* __restrict__ wk,
    const float* __restrict__ wv, const float* __restrict__ wo,
    bf16* __restrict__ wqkvb, bf16* __restrict__ wob) {
  size_t i4 = ((size_t)blockIdx.x * 256 + threadIdx.x) * 4;
  const float* src;
  bf16* dst;
  size_t off;
  if (i4 < 2097152UL)       { src = wq; dst = wqkvb;           off = i4; }
  else if (i4 < 4194304UL)  { src = wk; dst = wqkvb + 2097152; off = i4 - 2097152UL; }
  else if (i4 < 6291456UL)  { src = wv; dst = wqkvb + 4194304; off = i4 - 4194304UL; }
  else                      { src = wo; dst = wob;             off = i4 - 6291456UL; }
  float4 v = *(const float4*)(src + off);
  bf16x4 o;
  o[0] = (bf16)v.x; o[1] = (bf16)v.y; o[2] = (bf16)v.z; o[3] = (bf16)v.w;
  *(bf16x4*)(dst + off) = o;
}

// ---------------------------------------------------------------------------
// Per-head alpha.
// ---------------------------------------------------------------------------
__global__ __launch_bounds__(64) void alpha_kernel(
    const float* __restrict__ alpha_log, float* __restrict__ la_mean,
    float* __restrict__ la_d) {
  int h = blockIdx.x;
  int lane = threadIdx.x;
  float a1 = sigmoidf_(alpha_log[h * 128 + lane]);
  float a2 = sigmoidf_(alpha_log[h * 128 + 64 + lane]);
  la_d[h * 128 + lane] = logf(a1);
  la_d[h * 128 + 64 + lane] = logf(a2);
  float s = a1 + a2;
  for (int off = 32; off; off >>= 1) s += __shfl_down(s, off);
  if (lane == 0) la_mean[h] = logf(fmaxf(s * (1.0f / 128.0f), 1e-6f));
}

// ---------------------------------------------------------------------------
// beta[n,h] = sigmoid(x[n,:].Wb[h,:] + bb[h]); also emits xb = bf16(x).
// ---------------------------------------------------------------------------
__global__ __launch_bounds__(64) void beta_xb_kernel(
    const float* __restrict__ x, const float* __restrict__ Wb,
    const float* __restrict__ bbias, float* __restrict__ beta,
    bf16* __restrict__ xb) {
  int n = blockIdx.x;
  int lane = threadIdx.x;
  float acc[8];
#pragma unroll
  for (int h = 0; h < 8; h++) acc[h] = 0.0f;
  const float4* x4 = (const float4*)(x + (size_t)n * DMODEL);
  bf16* xbr = xb + (size_t)n * DMODEL;
  for (int d4 = lane; d4 < DMODEL / 4; d4 += 64) {
    float4 xv = x4[d4];
    bf16x4 o;
    o[0] = (bf16)xv.x; o[1] = (bf16)xv.y; o[2] = (bf16)xv.z; o[3] = (bf16)xv.w;
    *(bf16x4*)(xbr + d4 * 4) = o;
#pragma unroll
    for (int h = 0; h < 8; h++) {
      float4 wv = ((const float4*)(Wb + (size_t)h * DMODEL))[d4];
      acc[h] += xv.x * wv.x + xv.y * wv.y + xv.z * wv.z + xv.w * wv.w;
    }
  }
#pragma unroll
  for (int off = 32; off; off >>= 1)
#pragma unroll
    for (int h = 0; h < 8; h++) acc[h] += __shfl_down(acc[h], off);
  if (lane == 0) {
#pragma unroll
    for (int h = 0; h < 8; h++)
      beta[(size_t)n * 8 + h] = sigmoidf_(acc[h] + bbias[h]);
  }
}

// ---------------------------------------------------------------------------
// QKV projection: 128x384-tile 4-phase bf16 GEMM, FULL-FILL grid (256 blocks
// = 32 m-tiles x 8 n-panels, one n-panel per XCD so the 1.5MB B-panel pins
// in that XCD's L2; A (16MB) serves from L3).
//
// Geometry: BM=128, BN=384, BK=64, 8 waves (2M x 4N), per-wave 64x96 output
// (acc[4][6] f32x4), 12 MFMA per phase. LDS 128 KiB: 2 bufs x (A 16KB + B
// 48KB). B's LDS rows are PERMUTED (qn,wn,nfrag)-major: lds_row =
// qn*192 + wn*48 + nf*16 + r16  <->  global col = wn*96 + qn*48 + nf*16+r16,
// so each read-quadrant aligns with whole 64-row stage ops.
//
// Stage ops: 8 per K-tile (A:2, B:6), each = 512thr x 16B = 8KB = 64 rows.
// Schedule (phase walk 00->01->11->10, fragments held across phases):
//   p0: read A-q0(4 b128)+B-q0(6); stage B0,B1(t+1); MFMA acc[0..1][0..2]
//   p1: read B-q1(6);              stage B2,B3(t+1); MFMA acc[0..1][3..5]
//   p2: read A-q1(4, overwrite);   stage B4,B5(t+1); MFMA acc[2..3][3..5]
//   p3: no reads (B-q0 live);      stage A0,A1(t+2)! MFMA acc[2..3][0..2]
// p3 stages tile t+2's A into the CURRENT buffer (its A-region reads all
// complete at p2; two barriers separate) -> 5-phase staging window.
// vmcnt ledger (1 load/thread per stage op, 2 ops/phase):
//   p0: VMCNT(4) (last: VMCNT(0)) -> drains B3,B4,B5(t) read at p1
//   p3: VMCNT(5) (t=NT-2: VMCNT(3)) -> drains A0,A1,B0,B1,B2(t+1) for p0
// Min load age at drain = 2 phases. Swizzle: 16B-granule XOR (ldsrow&7),
// linear LDS dest + pre-swizzled global source (involution both sides).
// ---------------------------------------------------------------------------
#define QKV_K 2048
#define QKV_NT 32  // K / 64

__global__ __launch_bounds__(512, 2) void qkv_gemm8p_kernel(
    const bf16* __restrict__ A, const bf16* __restrict__ Bm,
    bf16* __restrict__ C, bf16* __restrict__ vt) {
  __shared__ __align__(16) bf16 smem[2][32768];  // buf: A[0,8192) B[8192,32768)

  // XCD-aware remap: 256 blocks = 8 XCDs x 32; each XCD owns one n-panel.
  const int id = blockIdx.x;
  const int wg = (id & 7) * 32 + (id >> 3);
  const int tile_n = (wg >> 5) * 384;
  const int tile_m = (wg & 31) * 128;

  const int tid = threadIdx.x;
  const int lane = tid & 63;
  const int w = tid >> 6;
  const int wm = w >> 2;  // 0..1 -> rows wm*64
  const int wn = w & 3;   // 0..3 -> cols wn*96
  const int lr = lane & 15;
  const int kq = lane >> 4;

  // staging lane constants (one stage op = 64 rows x 64k, 8KB)
  const int srow = lane >> 3;
  const int slot = lane & 7;
  const int sgo = (slot ^ srow) * 8;  // pre-swizzled global granule offset
  const int rloc = w * 8 + srow;      // 0..63 row within op

  size_t Aoff[2], Boff[6];
#pragma unroll
  for (int a = 0; a < 2; ++a)
    Aoff[a] = (size_t)(tile_m + a * 64 + rloc) * QKV_K + sgo;
#pragma unroll
  for (int b = 0; b < 6; ++b) {
    const int ldsr = b * 64 + rloc;
    const int qn = ldsr >= 192 ? 1 : 0;
    const int rem = ldsr - qn * 192;
    const int wng = rem / 48;
    const int rr = rem - wng * 48;
    const int gcol = wng * 96 + qn * 48 + rr;
    Boff[b] = (size_t)(tile_n + gcol) * QKV_K + sgo;
  }

  f32x4 acc[4][6];
#pragma unroll
  for (int i = 0; i < 4; i++)
#pragma unroll
    for (int j = 0; j < 6; j++) acc[i][j] = (f32x4){0.f, 0.f, 0.f, 0.f};

  auto stageAA = [&](int buf, int k0) {
#pragma unroll
    for (int a = 0; a < 2; ++a)
      gload_lds16(A + Aoff[a] + k0, &smem[buf][(a * 64 + w * 8) * 64]);
  };
  auto stageB2 = [&](int buf, int k0, int b0) {
#pragma unroll
    for (int u = 0; u < 2; ++u)
      gload_lds16(Bm + Boff[b0 + u] + k0,
                  &smem[buf][8192 + ((b0 + u) * 64 + w * 8) * 64]);
  };

  // prologue: tile0 fully (A first, then B), then tile1's A. Drain first-5.
  stageAA(0, 0);
  stageB2(0, 0, 0);
  stageB2(0, 0, 2);
  stageB2(0, 0, 4);
  stageAA(1, 64);
  VMCNT(5);
  BAR();

  for (int t = 0; t < QKV_NT; ++t) {
    const int buf = t & 1;
    const int k0n = (t + 1) * 64;
    const bool h1 = (t + 1 < QKV_NT);
    const bool h2 = (t + 2 < QKV_NT);
    const bf16* ldsA = smem[buf];
    const bf16* ldsB = smem[buf] + 8192;

    bf16x8 af[2][2], b0f[3][2], b1f[3][2];

    // ---- p0: read A-q0 + B-q0; stage B0,B1(t+1); MFMA (0,0) ----
#pragma unroll
    for (int mi = 0; mi < 2; ++mi)
#pragma unroll
      for (int ks = 0; ks < 2; ++ks)
        af[mi][ks] = *(const bf16x8*)&ldsA[(wm * 64 + mi * 16 + lr) * 64 +
                                           (((ks * 4 + kq) ^ (lr & 7)) * 8)];
#pragma unroll
    for (int ni = 0; ni < 3; ++ni)
#pragma unroll
      for (int ks = 0; ks < 2; ++ks)
        b0f[ni][ks] = *(const bf16x8*)&ldsB[(wn * 48 + ni * 16 + lr) * 64 +
                                            (((ks * 4 + kq) ^ (lr & 7)) * 8)];
    if (h1) stageB2(buf ^ 1, k0n, 0);
    BAR();
    __builtin_amdgcn_s_setprio(1);
#pragma unroll
    for (int mi = 0; mi < 2; ++mi)
#pragma unroll
      for (int ni = 0; ni < 3; ++ni)
#pragma unroll
        for (int ks = 0; ks < 2; ++ks)
          acc[mi][ni] = __builtin_amdgcn_mfma_f32_16x16x32_bf16(
              af[mi][ks], b0f[ni][ks], acc[mi][ni], 0, 0, 0);
    __builtin_amdgcn_s_setprio(0);
    if (h1) VMCNT(4);
    else VMCNT(0);
    BAR();

    // ---- p1: read B-q1; stage B2,B3(t+1); MFMA (0,1) ----
#pragma unroll
    for (int ni = 0; ni < 3; ++ni)
#pragma unroll
      for (int ks = 0; ks < 2; ++ks)
        b1f[ni][ks] = *(const bf16x8*)&ldsB[(192 + wn * 48 + ni * 16 + lr) * 64 +
                                            (((ks * 4 + kq) ^ (lr & 7)) * 8)];
    if (h1) stageB2(buf ^ 1, k0n, 2);
    BAR();
    __builtin_amdgcn_s_setprio(1);
#pragma unroll
    for (int mi = 0; mi < 2; ++mi)
#pragma unroll
      for (int ni = 0; ni < 3; ++ni)
#pragma unroll
        for (int ks = 0; ks < 2; ++ks)
          acc[mi][3 + ni] = __builtin_amdgcn_mfma_f32_16x16x32_bf16(
              af[mi][ks], b1f[ni][ks], acc[mi][3 + ni], 0, 0, 0);
    __builtin_amdgcn_s_setprio(0);
    BAR();

    // ---- p2: read A-q1 (overwrite); stage B4,B5(t+1); MFMA (1,1) ----
#pragma unroll
    for (int mi = 0; mi < 2; ++mi)
#pragma unroll
      for (int ks = 0; ks < 2; ++ks)
        af[mi][ks] = *(const bf16x8*)&ldsA[(wm * 64 + 32 + mi * 16 + lr) * 64 +
                                           (((ks * 4 + kq) ^ (lr & 7)) * 8)];
    if (h1) stageB2(buf ^ 1, k0n, 4);
    BAR();
    __builtin_amdgcn_s_setprio(1);
#pragma unroll
    for (int mi = 0; mi < 2; ++mi)
#pragma unroll
      for (int ni = 0; ni < 3; ++ni)
#pragma unroll
        for (int ks = 0; ks < 2; ++ks)
          acc[2 + mi][3 + ni] = __builtin_amdgcn_mfma_f32_16x16x32_bf16(
              af[mi][ks], b1f[ni][ks], acc[2 + mi][3 + ni], 0, 0, 0);
    __builtin_amdgcn_s_setprio(0);
    BAR();

    // ---- p3: no reads (B-q0 live); stage A(t+2) into CURRENT buf; MFMA (1,0)
    if (h2) stageAA(buf, (t + 2) * 64);
    BAR();
    __builtin_amdgcn_s_setprio(1);
#pragma unroll
    for (int mi = 0; mi < 2; ++mi)
#pragma unroll
      for (int ni = 0; ni < 3; ++ni)
#pragma unroll
        for (int ks = 0; ks < 2; ++ks)
          acc[2 + mi][ni] = __builtin_amdgcn_mfma_f32_16x16x32_bf16(
              af[mi][ks], b0f[ni][ks], acc[2 + mi][ni], 0, 0, 0);
    __builtin_amdgcn_s_setprio(0);
    if (h1) {
      if (h2) VMCNT(5);
      else VMCNT(3);
    }
    BAR();
  }

  // epilogue: acc -> q/kk/vv (+ vt for z==2)
  const int rb = kq * 4;
#pragma unroll
  for (int mi = 0; mi < 4; ++mi) {
    const int row0 = tile_m + wm * 64 + mi * 16 + rb;
#pragma unroll
    for (int ni = 0; ni < 6; ++ni) {
      const int col = tile_n + wn * 96 + ni * 16 + lr;
      const int z = col >> 10;
      const int cz = col & 1023;
      bf16* Cz = C + (size_t)z * 4194304UL;
#pragma unroll
      for (int r2 = 0; r2 < 4; ++r2)
        Cz[(size_t)(row0 + r2) * 1024 + cz] = (bf16)acc[mi][ni][r2];
      if (z == 2) {
        const int bb2 = row0 >> 11;
        const int ss = row0 & 2047;
        bf16x4 o4;
#pragma unroll
        for (int r2 = 0; r2 < 4; ++r2) o4[r2] = (bf16)acc[mi][ni][r2];
        *(bf16x4*)&vt[(((size_t)bb2 * 8 + (cz >> 7)) * 128 + (cz & 127)) * 2048 +
                      ss] = o4;
      }
    }
  }
}

// ---------------------------------------------------------------------------
// bf16 NT GEMM (round-3 config: BK=32, XOR bank swizzle, XCD tile swizzle).
// Retained for the output projection (obf=0, fp32 C).
// ---------------------------------------------------------------------------
__global__ __launch_bounds__(256) void gemm_bt_kernel(
    const bf16* __restrict__ A, const bf16* __restrict__ Bm, void* Cv, int K,
    int N, size_t strideB, size_t strideC, int obf, bf16* __restrict__ vt) {
  // ---- XCD-aware tile remap (bijective) ----
  const int id = blockIdx.x + gridDim.x * (blockIdx.y + gridDim.y * blockIdx.z);
  const int xcd = id & 7;
  const int s = id >> 3;
  const int xs = gridDim.x >> 2;
  const int ys = gridDim.y >> 1;
  const int perz = xs * ys;
  const int z = s / perz;
  const int r = s - z * perz;
  const int tx = (xcd & 3) * xs + (r % xs);
  const int ty = (xcd >> 2) * ys + (r / xs);
  const int tile_n = tx * 128;
  const int tile_m = ty * 128;

  const bf16* Bp = Bm + (size_t)z * strideB;
  const int tid = threadIdx.x;
  const int lane = tid & 63;
  const int wv = tid >> 6;

  __shared__ bf16 As[128 * 32];
  __shared__ bf16 Bs[128 * 32];

  f32x4 acc[4][4];
#pragma unroll
  for (int i = 0; i < 4; i++)
#pragma unroll
    for (int j = 0; j < 4; j++) acc[i][j] = (f32x4){0.f, 0.f, 0.f, 0.f};

  const int wm = (wv >> 1) * 64;
  const int wn = (wv & 1) * 64;
  const int lr = lane & 15;
  const int kq = lane >> 4;
  const int swzA = ((wm + lr) >> 1) & 3;
  const int swzB = ((wn + lr) >> 1) & 3;
  const int kA = (kq ^ swzA) * 8;
  const int kB = (kq ^ swzB) * 8;

  const int ar = wv * 32 + (lane >> 2);
  const int g = ((lane & 3) ^ ((ar >> 1) & 3)) * 8;
  const bf16* Ag = A + (size_t)(tile_m + ar) * K + g;
  const bf16* Bg = Bp + (size_t)(tile_n + ar) * K + g;
  bf16* AsW = &As[wv * 1024];
  bf16* BsW = &Bs[wv * 1024];

  for (int k0 = 0; k0 < K; k0 += 32) {
    gload_lds16(Ag + k0, AsW);
    gload_lds16(Ag + (size_t)16 * K + k0, AsW + 512);
    gload_lds16(Bg + k0, BsW);
    gload_lds16(Bg + (size_t)16 * K + k0, BsW + 512);
    __syncthreads();
    bf16x8 af[4], bfr[4];
#pragma unroll
    for (int mi = 0; mi < 4; mi++)
      af[mi] = *(const bf16x8*)&As[(wm + mi * 16 + lr) * 32 + kA];
#pragma unroll
    for (int ni = 0; ni < 4; ni++)
      bfr[ni] = *(const bf16x8*)&Bs[(wn + ni * 16 + lr) * 32 + kB];
#pragma unroll
    for (int mi = 0; mi < 4; mi++)
#pragma unroll
      for (int ni = 0; ni < 4; ni++)
        acc[mi][ni] = __builtin_amdgcn_mfma_f32_16x16x32_bf16(
            af[mi], bfr[ni], acc[mi][ni], 0, 0, 0);
    __syncthreads();
  }

  const int crow0 = tile_m + wm + (lane >> 4) * 4;
  const int ccol = tile_n + wn + (lane & 15);
  if (obf) {
    bf16* Cb = (bf16*)Cv + (size_t)z * strideC;
#pragma unroll
    for (int mi = 0; mi < 4; mi++)
#pragma unroll
      for (int ni = 0; ni < 4; ni++)
#pragma unroll
        for (int r2 = 0; r2 < 4; r2++)
          Cb[(size_t)(crow0 + mi * 16 + r2) * N + ccol + ni * 16] =
              (bf16)acc[mi][ni][r2];
    if (z == 2) {
#pragma unroll
      for (int mi = 0; mi < 4; mi++) {
        int row0 = crow0 + mi * 16;
        int bb2 = row0 >> 11, ss = row0 & 2047;
#pragma unroll
        for (int ni = 0; ni < 4; ni++) {
          int col = ccol + ni * 16;
          bf16x4 o4;
#pragma unroll
          for (int r2 = 0; r2 < 4; r2++) o4[r2] = (bf16)acc[mi][ni][r2];
          *(bf16x4*)&vt[(((size_t)bb2 * 8 + (col >> 7)) * 128 + (col & 127)) *
                            2048 +
                        ss] = o4;
        }
      }
    }
  } else {
    float* Cf = (float*)Cv + (size_t)z * strideC;
#pragma unroll
    for (int mi = 0; mi < 4; mi++)
#pragma unroll
      for (int ni = 0; ni < 4; ni++)
#pragma unroll
        for (int r2 = 0; r2 < 4; r2++)
          Cf[(size_t)(crow0 + mi * 16 + r2) * N + ccol + ni * 16] =
              acc[mi][ni][r2];
  }
}

// ---------------------------------------------------------------------------
// RoPE in place on bf16 q and k.
// ---------------------------------------------------------------------------
__global__ __launch_bounds__(256) void rope_kernel(bf16* __restrict__ q,
                                                   bf16* __restrict__ k) {
  int idx = blockIdx.x * 256 + threadIdx.x;  // < 524288
  int j0 = (idx & 15) * 4;
  int nh = idx >> 4;  // n*8 + h, n < 4096
  int s = (nh >> 3) & (S_LEN - 1);
  size_t base = (size_t)nh * 128 + j0;
  bf16x4 qa = *(bf16x4*)&q[base], qb = *(bf16x4*)&q[base + 64];
  bf16x4 ka = *(bf16x4*)&k[base], kb = *(bf16x4*)&k[base + 64];
#pragma unroll
  for (int jj = 0; jj < 4; jj++) {
    float inv = expf(-(float)(j0 + jj) * (9.210340371976184f / 64.0f));
    float f = (float)s * inv;
    float sn, c;
    sincosf(f, &sn, &c);
    float q1 = (float)qa[jj], q2 = (float)qb[jj];
    qa[jj] = (bf16)(q1 * c - q2 * sn);
    qb[jj] = (bf16)(q2 * c + q1 * sn);
    float k1 = (float)ka[jj], k2 = (float)kb[jj];
    ka[jj] = (bf16)(k1 * c - k2 * sn);
    kb[jj] = (bf16)(k2 * c + k1 * sn);
  }
  *(bf16x4*)&q[base] = qa;
  *(bf16x4*)&q[base + 64] = qb;
  *(bf16x4*)&k[base] = ka;
  *(bf16x4*)&k[base + 64] = kb;
}

// ---------------------------------------------------------------------------
// MFMA banded-decay attention. One block per (s-block 64, h, b); 4 waves,
// each wave owns 16 q rows. QK^T and PV via 16x16x32 bf16 MFMA.
// ---------------------------------------------------------------------------
__global__ __launch_bounds__(256) void attn_mfma_kernel(
    const bf16* __restrict__ q, const bf16* __restrict__ k,
    const bf16* __restrict__ vt, const float* __restrict__ beta,
    const float* __restrict__ la_mean, bf16* __restrict__ outb) {
  const int s0 = blockIdx.x * 64;
  const int h = blockIdx.y;
  const int b = blockIdx.z;
  const int tid = threadIdx.x;
  const int w = tid >> 6;
  const int lane = tid & 63;
  const int lr = lane & 15;
  const int kq = lane >> 4;  // quad
  const float la = la_mean[h];

  __shared__ __align__(16) bf16 Ps[4][2][16][72];

  const int sg = s0 + w * 16;
  const size_t qbase =
      ((size_t)b * S_LEN + (sg + lr)) * INNER_DIM + h * 128 + kq * 8;
  bf16x8 aq[4];
#pragma unroll
  for (int ks = 0; ks < 4; ks++)
    aq[ks] = *(const bf16x8*)&q[qbase + ks * 32];

  f32x4 O[8];
#pragma unroll
  for (int en = 0; en < 8; en++) O[en] = (f32x4){0.f, 0.f, 0.f, 0.f};

  const size_t kbase = (size_t)b * S_LEN * INNER_DIM + h * 128 + kq * 8;
  const size_t vtbase = ((size_t)b * 8 + h) * 128 * 2048;

#pragma unroll
  for (int tile = 0; tile < 2; tile++) {
    const int tb = s0 - 64 + tile * 64;
    f32x4 sc[4];
#pragma unroll
    for (int nt = 0; nt < 4; nt++) sc[nt] = (f32x4){0.f, 0.f, 0.f, 0.f};
#pragma unroll
    for (int nt = 0; nt < 4; nt++) {
      int t = tb + nt * 16 + lr;
      int tc = t > 0 ? t : 0;
#pragma unroll
      for (int ks = 0; ks < 4; ks++) {
        bf16x8 bk = *(const bf16x8*)&k[kbase + (size_t)tc * INNER_DIM + ks * 32];
        sc[nt] = __builtin_amdgcn_mfma_f32_16x16x32_bf16(aq[ks], bk, sc[nt],
                                                         0, 0, 0);
      }
    }
#pragma unroll
    for (int nt = 0; nt < 4; nt++) {
      int t = tb + nt * 16 + lr;
      int tc = t > 0 ? t : 0;
      float bt = beta[((size_t)b * S_LEN + tc) * 8 + h];
#pragma unroll
      for (int reg = 0; reg < 4; reg++) {
        int qrow = sg + kq * 4 + reg;
        int td = qrow - t;
        float wgt = 0.0f;
        if (t >= 0 && td >= 0 && td < 64)
          wgt = sc[nt][reg] * __expf((float)td * la) * bt;
        Ps[w][tile][kq * 4 + reg][nt * 16 + lr] = (bf16)wgt;
      }
    }
    __syncthreads();
    bf16x8 ap[2];
#pragma unroll
    for (int ks2 = 0; ks2 < 2; ks2++)
      ap[ks2] = *(const bf16x8*)&Ps[w][tile][lr][ks2 * 32 + kq * 8];
#pragma unroll
    for (int en = 0; en < 8; en++) {
#pragma unroll
      for (int ks2 = 0; ks2 < 2; ks2++) {
        int t0f = tb + ks2 * 32 + kq * 8;
        int tcf = t0f > 0 ? t0f : 0;
        bf16x8 bv = *(const bf16x8*)&vt[vtbase + (size_t)(en * 16 + lr) * 2048 +
                                        tcf];
        O[en] = __builtin_amdgcn_mfma_f32_16x16x32_bf16(ap[ks2], bv, O[en], 0,
                                                        0, 0);
      }
    }
  }
  const size_t obase = (size_t)b * S_LEN * INNER_DIM + h * 128;
#pragma unroll
  for (int en = 0; en < 8; en++) {
#pragma unroll
    for (int reg = 0; reg < 4; reg++) {
      int qrow = sg + kq * 4 + reg;
      outb[obase + (size_t)qrow * INNER_DIM + en * 16 + lr] =
          (bf16)O[en][reg];
    }
  }
}

// ---------------------------------------------------------------------------
// Stage 1: partial state per 32-step chunk (bf16 k/v inputs), no atomics.
// ---------------------------------------------------------------------------
__global__ __launch_bounds__(256) void state_partial_kernel(
    const bf16* __restrict__ k, const bf16* __restrict__ v,
    const float* __restrict__ beta, const float* __restrict__ la_d,
    float* __restrict__ part) {
  const int bh = blockIdx.x;
  const int chunk = blockIdx.y;
  const int b = bh >> 3, h = bh & 7;
  const int t0 = S_LEN - 512 + chunk * 32;
  const int tid = threadIdx.x;
  const int d = tid >> 1;
  const int eh = (tid & 1) * 64;

  __shared__ float ks[32][128];
  __shared__ float vsm[32][128];
  __shared__ float bs[32];

  const size_t bh_off = ((size_t)b * S_LEN) * INNER_DIM + (size_t)h * 128;
  for (int u = tid; u < 32 * 16; u += 256) {
    int r = u >> 4, c8 = (u & 15) * 8;
    bf16x8 kv = *(const bf16x8*)&k[bh_off + (size_t)(t0 + r) * INNER_DIM + c8];
    bf16x8 vv = *(const bf16x8*)&v[bh_off + (size_t)(t0 + r) * INNER_DIM + c8];
#pragma unroll
    for (int j = 0; j < 8; j++) {
      ks[r][c8 + j] = (float)kv[j];
      vsm[r][c8 + j] = (float)vv[j];
    }
  }
  if (tid < 32) bs[tid] = beta[((size_t)b * S_LEN + t0 + tid) * 8 + h];
  __syncthreads();

  const float lad = la_d[h * 128 + d];
  float acc[64];
#pragma unroll
  for (int e = 0; e < 64; e++) acc[e] = 0.0f;

  for (int tl = 0; tl < 32; tl++) {
    int m = (S_LEN - 1) - (t0 + tl);
    float f = __expf((float)m * lad);
    float coef = bs[tl] * ks[tl][d] * f;
    if (coef != 0.0f) {
#pragma unroll
      for (int e = 0; e < 64; e += 4) {
        float4 vv = *(const float4*)&vsm[tl][eh + e];
        acc[e + 0] = fmaf(coef, vv.x, acc[e + 0]);
        acc[e + 1] = fmaf(coef, vv.y, acc[e + 1]);
        acc[e + 2] = fmaf(coef, vv.z, acc[e + 2]);
        acc[e + 3] = fmaf(coef, vv.w, acc[e + 3]);
      }
    }
  }
  float* pp = part + (((size_t)chunk * 16 + bh) * 16384 + (size_t)d * 128 + eh);
#pragma unroll
  for (int e = 0; e < 64; e += 4) {
    float4 o = {acc[e + 0], acc[e + 1], acc[e + 2], acc[e + 3]};
    *(float4*)&pp[e] = o;
  }
}

// ---------------------------------------------------------------------------
// Stage 2: sum the 16 chunk partials into the final state.
// ---------------------------------------------------------------------------
__global__ __launch_bounds__(256) void state_reduce_kernel(
    const float* __restrict__ part, float* __restrict__ state) {
  size_t off = ((size_t)blockIdx.x * 256 + threadIdx.x) * 4;
  float4 s = {0.f, 0.f, 0.f, 0.f};
#pragma unroll
  for (int c = 0; c < 16; c++) {
    float4 p = *(const float4*)&part[(size_t)c * 262144 + off];
    s.x += p.x; s.y += p.y; s.z += p.z; s.w += p.w;
  }
  *(float4*)&state[off] = s;
}

// ---------------------------------------------------------------------------
extern "C" void kernel_launch(void* const* d_in, const int* in_sizes, int n_in,
                              void* d_out, int out_size, void* d_ws,
                              size_t ws_size, hipStream_t stream) {
  const float* x = (const float*)d_in[0];
  const float* Wq = (const float*)d_in[1];
  const float* Wk = (const float*)d_in[2];
  const float* Wv = (const float*)d_in[3];
  const float* Wo = (const float*)d_in[4];
  const float* Wb = (const float*)d_in[5];
  const float* bb = (const float*)d_in[6];
  const float* alog = (const float*)d_in[7];
  float* out = (float*)d_out;

  char* ws = (char*)d_ws;
  bf16* xb = (bf16*)(ws);                      // 16 MB
  float* part = (float*)(ws);                  // reuses xb after QKV GEMM
  bf16* wqkvb = (bf16*)(ws + 16777216UL);      // 12 MB
  bf16* wob = (bf16*)(ws + 29360128UL);        // 4 MB
  bf16* q = (bf16*)(ws + 33554432UL);          // 8 MB
  bf16* kk = (bf16*)(ws + 41943040UL);         // 8 MB
  bf16* vv = (bf16*)(ws + 50331648UL);         // 8 MB
  bf16* attnb = (bf16*)(ws + 58720256UL);      // 8 MB
  bf16* vt = (bf16*)(ws + 67108864UL);         // 8 MB (V transposed)
  float* beta = (float*)(ws + 75497472UL);     // 128 KB
  float* la_mean = (float*)(ws + 75628544UL);  // 32 B
  float* la_d = (float*)(ws + 75628800UL);     // 4 KB

  convert_w_kernel<<<8192, 256, 0, stream>>>(Wq, Wk, Wv, Wo, wqkvb, wob);
  alpha_kernel<<<8, 64, 0, stream>>>(alog, la_mean, la_d);
  beta_xb_kernel<<<BATCH * S_LEN, 64, 0, stream>>>(x, Wb, bb, beta, xb);
  // fused QKV GEMM (128x384 4-phase, full-fill 256 blocks) -> q/kk/vv (+ vt)
  qkv_gemm8p_kernel<<<256, 512, 0, stream>>>(xb, wqkvb, q, vt);
  rope_kernel<<<2048, 256, 0, stream>>>(q, kk);
  attn_mfma_kernel<<<dim3(S_LEN / 64, NHEADS, BATCH), 256, 0, stream>>>(
      q, kk, vt, beta, la_mean, attnb);
  state_partial_kernel<<<dim3(16, 16), 256, 0, stream>>>(kk, vv, beta, la_d,
                                                         part);
  state_reduce_kernel<<<256, 256, 0, stream>>>(part, out + 8388608);
  gemm_bt_kernel<<<dim3(DMODEL / 128, (BATCH * S_LEN) / 128, 1), 256, 0,
                   stream>>>(attnb, wob, out, INNER_DIM, DMODEL, 0, 0, 0,
                             nullptr);
}